// Round 6
// baseline (245.372 us; speedup 1.0000x reference)
//
#include <hip/hip_runtime.h>
#include <hip/hip_bf16.h>

namespace {
constexpr int kB   = 1000;
constexpr int kT   = 20000;
constexpr int kKt  = 181;
constexpr int kInW = kT + kKt - 1;            // 20180
constexpr int CH     = 256;                   // staging chunk = 256 input cols
constexpr int STRIDE = CH + 8;                // 264 shorts/row: +8 pad -> no extra bank conflicts
constexpr int SLOT   = 16 * STRIDE;           // 4224 shorts per ring slot
constexpr int SPB    = 4;                     // strips per block
constexpr int NSTRIP = (kT + CH - 1) / CH;    // 79
constexpr int NSG    = (NSTRIP + SPB - 1) / SPB;  // 20
constexpr int NBG    = (kB + 15) / 16;        // 63
constexpr int NBLK   = NBG * NSG;             // 1260 blocks ~ 5/CU, all co-resident

typedef short bf16x8 __attribute__((ext_vector_type(8)));
typedef float f32x4  __attribute__((ext_vector_type(4)));

__device__ __forceinline__ unsigned pack_bf16x2(float lo, float hi) {
  __hip_bfloat162 h = __float22bfloat162_rn(float2{lo, hi});
  unsigned w;
  __builtin_memcpy(&w, &h, 4);
  return w;
}
__device__ __forceinline__ short f32_bf16(float f) {
  union { float f; unsigned u; } x; x.f = f;
  unsigned r = x.u + (0x7fffu + ((x.u >> 16) & 1u));
  return (short)(r >> 16);
}
} // namespace

__global__ __launch_bounds__(256, 5)
void biexp_pipe(const float* __restrict__ u, const float* __restrict__ kern,
                float* __restrict__ out) {
  __shared__ short lds_a[3 * SLOT];   // 25,344 B ring: 3 chunks x 16 rows x 264 bf16
  __shared__ float lds_k[kKt];

  const int tid = threadIdx.x;
  if (tid < kKt) lds_k[tid] = kern[tid];

  const int bx = blockIdx.x;
  const int jb = bx % NBG;            // row group
  const int sg = bx / NBG;            // strip group
  const int b0 = jb * 16;
  const int s0 = sg * SPB;

  const int lane = tid & 63;
  const int wave = tid >> 6;
  const int quad = lane >> 4;
  const int nn   = lane & 15;

  // ---- staging thread mapping: thread t -> row t>>4, 4 interleaved f32x4 (coalesced 1KB/instr)
  const int srow = tid >> 4;
  const int scol = (tid & 15) * 4;
  const float* __restrict__ srcrow = u + (size_t)min(b0 + srow, kB - 1) * kInW;

  auto issue = [&](int c, f32x4 v[4]) {            // global -> regs (no wait here)
    const int base = CH * c + scol;
    if (CH * (c + 1) <= kInW) {                    // wave-uniform fast path (chunks 0..77)
      #pragma unroll
      for (int i = 0; i < 4; ++i) v[i] = *(const f32x4*)(srcrow + base + 64 * i);
    } else {                                       // tail chunks 78,79: per-element clamp
      #pragma unroll
      for (int i = 0; i < 4; ++i)
        #pragma unroll
        for (int j = 0; j < 4; ++j) v[i][j] = srcrow[min(base + 64 * i + j, kInW - 1)];
    }
  };
  auto commit = [&](int c, const f32x4 v[4]) {     // regs -> bf16 -> LDS ring slot c%3
    short* dst = &lds_a[(c % 3) * SLOT + srow * STRIDE + scol];
    #pragma unroll
    for (int i = 0; i < 4; ++i) {
      short4 s;
      s.x = f32_bf16(v[i][0]); s.y = f32_bf16(v[i][1]);
      s.z = f32_bf16(v[i][2]); s.w = f32_bf16(v[i][3]);
      *(short4*)(dst + 64 * i) = s;
    }
  };

  // ---- prologue: stage chunks s0, s0+1 (latency exposed once per block)
  f32x4 vA[4], vB[4];
  issue(s0, vA);
  issue(s0 + 1, vB);
  commit(s0, vA);
  commit(s0 + 1, vB);
  __syncthreads();                                 // covers lds_k too

  // ---- Toeplitz B fragments: B[k][n] = w(k-n), w(i)=kern[180-i] (verified R5)
  union { bf16x8 v; unsigned w[4]; } bfr[7];
  #pragma unroll
  for (int c = 0; c < 7; ++c)
    #pragma unroll
    for (int jj = 0; jj < 4; ++jj) {
      int i0 = 32 * c + quad * 8 + 2 * jj - nn;
      float f0 = (i0 >= 0     && i0 < kKt)     ? lds_k[kKt - 1 - i0] : 0.0f;
      float f1 = (i0 + 1 >= 0 && i0 + 1 < kKt) ? lds_k[kKt - 2 - i0] : 0.0f;
      bfr[c].w[jj] = pack_bf16x2(f0, f1);
    }

  // ---- strip loop: prefetch chunk s+2 across the compute phase, one barrier/strip
  const int colw = 64 * wave + 8 * quad;           // lane's col base within strip
  for (int k = 0; k < SPB; ++k) {
    const int s = s0 + k;
    if (s >= NSTRIP) break;                        // block-uniform
    const bool pf = (k + 1 < SPB) && (s + 1 < NSTRIP);
    if (pf) issue(s + 2, vA);                      // loads in flight across compute

    const int T0 = s * CH;
    const int slotA = (s % 3) * SLOT;
    const int slotB = ((s + 1) % 3) * SLOT;
    const short* lrow = &lds_a[nn * STRIDE];

    #pragma unroll
    for (int jt = 0; jt < 4; ++jt) {
      f32x4 acc0 = {0.f, 0.f, 0.f, 0.f};
      f32x4 acc1 = {0.f, 0.f, 0.f, 0.f};
      #pragma unroll
      for (int c = 0; c < 7; ++c) {
        const int off = colw + 16 * jt + 32 * c;   // < 512; spans at most 2 chunks
        const int within = off & 255;              // 8-aligned -> 16B-aligned reads
        const short* p = lrow + ((off >> 8) ? slotB : slotA) + within;
        bf16x8 a = *(const bf16x8*)p;
        if (c & 1) acc1 = __builtin_amdgcn_mfma_f32_16x16x32_bf16(a, bfr[c].v, acc1, 0, 0, 0);
        else       acc0 = __builtin_amdgcn_mfma_f32_16x16x32_bf16(a, bfr[c].v, acc0, 0, 0, 0);
      }
      const int gt = T0 + 64 * wave + 16 * jt + nn;
      #pragma unroll
      for (int r = 0; r < 4; ++r) {
        const int gb = b0 + quad * 4 + r;          // C/D: col=lane&15, row=quad*4+r (m89)
        if (gb < kB && gt < kT) out[(size_t)gb * kT + gt] = acc0[r] + acc1[r];
      }
    }

    if (pf) commit(s + 2, vA);                     // waitcnt here: ~3000 cyc after issue
    __syncthreads();
  }
}

extern "C" void kernel_launch(void* const* d_in, const int* in_sizes, int n_in,
                              void* d_out, int out_size, void* d_ws, size_t ws_size,
                              hipStream_t stream) {
  const float* u  = (const float*)d_in[0];
  const float* kn = (const float*)d_in[1];
  float* out = (float*)d_out;
  hipLaunchKernelGGL(biexp_pipe, dim3(NBLK, 1, 1), dim3(256, 1, 1), 0, stream,
                     u, kn, out);
}